// Round 4
// baseline (1120.302 us; speedup 1.0000x reference)
//
#include <hip/hip_runtime.h>
#include <stdint.h>
#include <math.h>

// Problem constants (B=4,S=2048 -> T=8192; H=1024; 2H=2048; E=8; K=2)
#define T_TOK 8192
#define H_DIM 1024
#define H2    2048
#define NE    8

typedef unsigned short u16;
typedef __attribute__((ext_vector_type(8))) short bf16x8;   // 8 bf16 in 4 VGPRs
typedef __attribute__((ext_vector_type(4))) float f32x4;    // MFMA 16x16 C/D

__device__ __forceinline__ u16 f32_to_bf16(float f) {
  union { float f; unsigned u; } c; c.f = f;
  unsigned u = c.u + 0x7fffu + ((c.u >> 16) & 1u);  // RNE
  return (u16)(u >> 16);
}
__device__ __forceinline__ float bf2f(u16 v) {
  union { unsigned u; float f; } c; c.u = (unsigned)v << 16; return c.f;
}
// pack two f32 -> two RNE bf16 in one u32 (lo in low half)
__device__ __forceinline__ unsigned pk_bf16(float lo, float hi) {
  union { float f; unsigned u; } a, b; a.f = lo; b.f = hi;
  unsigned ua = a.u + 0x7fffu + ((a.u >> 16) & 1u);
  unsigned ub = b.u + 0x7fffu + ((b.u >> 16) & 1u);
  return (ua >> 16) | (ub & 0xffff0000u);
}

// fast gelu (tanh form), |err| vs exact erf-gelu <= ~1e-3 (absmax 1.56e-2
// vs threshold 4.9e-2, stable across rounds)
__device__ __forceinline__ float fast_gelu(float v) {
  float u = v * v;
  float z2 = v * fmaf(u, 0.1029437f, 2.3022078f);
  float e = __builtin_amdgcn_exp2f(z2);
  float r = __builtin_amdgcn_rcpf(1.0f + e);
  return v - v * r;
}

// async global->LDS, 16B per lane. LDS dest is wave-uniform base + lane*16;
// global address is per-lane (exploited for the XOR bank swizzle).
__device__ __forceinline__ void g2l16(const void* g, void* l) {
  __builtin_amdgcn_global_load_lds(
      (const __attribute__((address_space(1))) unsigned*)g,
      (__attribute__((address_space(3))) unsigned*)l, 16, 0, 0);
}

// exclusive prefix of 8 counts, computed per-block
__device__ __forceinline__ int prefix_base(const int* counts, int e) {
  int b = 0;
#pragma unroll
  for (int j = 0; j < NE; j++) b += (j < e) ? counts[j] : 0;
  return b;
}

// ---------------- Prep: router only (weight cvt now fused into the GEMMs).
// One wave per token; fp64 logits -> exact ranking vs reference top-k.
// Also zeroes counts (build runs after prep completes).
__global__ __launch_bounds__(256) void prep_kernel(
    const float* __restrict__ x, const float* __restrict__ rw,
    u16* __restrict__ xb, int* __restrict__ tope, float2* __restrict__ gate2,
    int* __restrict__ counts) {
  int blk = blockIdx.x;
  if (blk == 0 && threadIdx.x < NE) counts[threadIdx.x] = 0;
  int wave = threadIdx.x >> 6;
  int lane = threadIdx.x & 63;
  int t = blk * 4 + wave;
  const float4* x4 = (const float4*)(x + (size_t)t * H_DIM);
  const float4* rw4 = (const float4*)rw;
  u16* xbrow = xb + (size_t)t * H_DIM;

  double acc[NE];
#pragma unroll
  for (int e = 0; e < NE; e++) acc[e] = 0.0;
#pragma unroll
  for (int i = 0; i < 4; i++) {
    int c = lane + 64 * i;
    float4 xv = x4[c];
    ushort4 bv = make_ushort4(f32_to_bf16(xv.x), f32_to_bf16(xv.y),
                              f32_to_bf16(xv.z), f32_to_bf16(xv.w));
    *(ushort4*)(xbrow + c * 4) = bv;
#pragma unroll
    for (int e = 0; e < NE; e++) {
      float4 wv = rw4[e * 256 + c];
      acc[e] += (double)xv.x * wv.x + (double)xv.y * wv.y +
                (double)xv.z * wv.z + (double)xv.w * wv.w;
    }
  }
#pragma unroll
  for (int off = 32; off >= 1; off >>= 1)
#pragma unroll
    for (int e = 0; e < NE; e++) acc[e] += __shfl_xor(acc[e], off, 64);

  if (lane == 0) {
    int e0 = 0; double v0 = acc[0];
#pragma unroll
    for (int e = 1; e < NE; e++) if (acc[e] > v0) { v0 = acc[e]; e0 = e; }
    int e1 = -1; double v1 = -1e300;
#pragma unroll
    for (int e = 0; e < NE; e++) if (e != e0 && acc[e] > v1) { v1 = acc[e]; e1 = e; }
    double ex = exp(v1 - v0);
    tope[t] = e0 | (e1 << 8);
    gate2[t] = make_float2((float)(1.0 / (1.0 + ex)), (float)(ex / (1.0 + ex)));
  }
}

// ---------------- Build expert lists: counting sort over 8 bins.
__global__ __launch_bounds__(256) void build_kernel(
    const int* __restrict__ tope, int* __restrict__ counts,
    int* __restrict__ tok_list, int2* __restrict__ pos2) {
  __shared__ int cts[4][NE];
  __shared__ int gbase[NE];
  int tid = threadIdx.x, lane = tid & 63, w = tid >> 6;
  int t = blockIdx.x * 256 + tid;
  int pk = tope[t];
  int e0 = pk & 0xff, e1 = (pk >> 8) & 0xff;
  unsigned long long lt = ((unsigned long long)1 << lane) - 1;

  int r0 = 0, r1 = 0;
#pragma unroll
  for (int e = 0; e < NE; e++) {
    unsigned long long b0 = __ballot(e0 == e);
    unsigned long long b1 = __ballot(e1 == e);
    int n0 = __popcll(b0), n1 = __popcll(b1);
    if (e0 == e) r0 = __popcll(b0 & lt);
    if (e1 == e) r1 = n0 + __popcll(b1 & lt);
    if (lane == 0) cts[w][e] = n0 + n1;
  }
  __syncthreads();
  if (tid < NE) {
    int bt = cts[0][tid] + cts[1][tid] + cts[2][tid] + cts[3][tid];
    gbase[tid] = atomicAdd(&counts[tid], bt);
  }
  __syncthreads();
  int off0 = gbase[e0] + r0;
  int off1 = gbase[e1] + r1;
#pragma unroll
  for (int wp = 0; wp < 4; wp++) {
    if (wp < w) { off0 += cts[wp][e0]; off1 += cts[wp][e1]; }
  }
  tok_list[e0 * T_TOK + off0] = t;
  tok_list[e1 * T_TOK + off1] = t;
  pos2[t] = make_int2(off0, off1);
}

// ---------------- Grouped GEMM: R3 minimum-sync double-buffer schedule,
// now with (a) B staged directly from f32 weights (reg-stage: dwordx4 loads
// issued at tile top, RNE-packed + swizzled ds_write AFTER the MFMA cluster
// so the latency+VALU hide under 2484 cyc of MFMA), eliminating the prep
// weight-conversion pass; (b) optional K-split (KSPLIT output partials,
// summed in combine) to shrink job granularity / makespan quantization.
//
// Per K-tile t (buf d = t&1): one {vmcnt(0) lgkmcnt(0); s_barrier}; issue
// B(t+1) f32 loads + A(t+1) g2l16; 24 ds_read_b128 of tile t; 64 MFMA
// (setprio); then cvt+ds_write B(t+1). WAR-safe: all waves passed the top
// barrier only after their MFMAs of t-1 (which consumed buf d^1) retired.
//
// XOR swizzle: phys 16B-chunk = logical ^ (row&7). A: pre-swizzled global
// source + linear LDS dest (g2l16). B: direct swizzled ds_write. Reads use
// the same XOR. XCD pinning: e = blockIdx&7 (bijective, grid%8==0).
template <int NKT, int NT, int KFULL, int KSPLIT, int OUTN, bool GATHER, bool GELU>
__global__ __launch_bounds__(512, 2) void moe_gemm(
    const u16* __restrict__ A, const float* __restrict__ Wf,
    u16* __restrict__ O, const int* __restrict__ tok_list,
    const int* __restrict__ counts) {
  int e = blockIdx.x & 7;
  int rem = blockIdx.x >> 3;
  int nt = rem % NT;
  int mtk = rem / NT;
  int mt = mtk & 31;
  int kh = mtk >> 5;                       // 0..KSPLIT-1
  int cnt = counts[e];
  int m0 = mt * 256;
  if (m0 >= cnt) return;
  int base = prefix_base(counts, e);
  const int k0 = kh * NKT * 64;
  O += (size_t)kh * 2 * T_TOK * OUTN;      // partial-sum buffer for this split

  __shared__ u16 lA[2][16384];   // [dbuf][256][64] bf16 = 64 KB
  __shared__ u16 lB[2][16384];   // 64 KB

  int tid = threadIdx.x;
  int ln = tid & 63, w = tid >> 6;
  int wr = w >> 2, wc = w & 3;             // 2M x 4N wave grid
  int quad = ln >> 4, l16 = ln & 15;

  // ---- A staging (g2l16): call c covers rows c*64..+63; 16B unit u;
  // phys slot u&7 holds global chunk (u&7)^(row&7).
  const u16* aptr[4];
#pragma unroll
  for (int c = 0; c < 4; ++c) {
    int u = c * 512 + tid;
    int row = u >> 3;
    int chunk = (u & 7) ^ (row & 7);
    int ar = m0 + row; if (ar > cnt - 1) ar = cnt - 1;
    const u16* ab;
    if (GATHER) ab = A + (size_t)tok_list[e * T_TOK + ar] * KFULL;
    else        ab = A + (size_t)(base + ar) * KFULL;
    aptr[c] = ab + k0 + chunk * 8;
  }

  // ---- B staging (reg): thread -> row tid>>1, f32 cols (tid&1)*32..+31
  const int rB = tid >> 1, hf = tid & 1;
  const float4* bsrc = (const float4*)(
      Wf + (size_t)e * OUTN * KFULL + (size_t)(nt * 256 + rB) * KFULL +
      k0 + hf * 32);
  const int rB7 = rB & 7, hf4 = hf * 4;

  // ---- read addresses (u16 within one 16384-u16 buffer)
  int adA[8][2], adB[4][2];
#pragma unroll
  for (int f = 0; f < 8; ++f) {
    int r = wr * 128 + f * 16 + l16;
#pragma unroll
    for (int kk = 0; kk < 2; ++kk)
      adA[f][kk] = r * 64 + ((((kk << 2) | quad) ^ (r & 7)) << 3);
  }
#pragma unroll
  for (int j = 0; j < 4; ++j) {
    int r = wc * 64 + j * 16 + l16;
#pragma unroll
    for (int kk = 0; kk < 2; ++kk)
      adB[j][kk] = r * 64 + ((((kk << 2) | quad) ^ (r & 7)) << 3);
  }

  f32x4 acc[8][4];
#pragma unroll
  for (int i = 0; i < 8; i++)
#pragma unroll
    for (int j = 0; j < 4; j++)
#pragma unroll
      for (int r = 0; r < 4; r++) acc[i][j][r] = 0.f;

  // ---- prologue: tile 0 (B via regs, A via g2l16)
  {
    float4 bv[8];
#pragma unroll
    for (int j = 0; j < 8; ++j) bv[j] = bsrc[j];
#pragma unroll
    for (int c = 0; c < 4; ++c) g2l16(aptr[c], &lA[0][(c * 512 + tid) * 8]);
    u16* wb = &lB[0][rB * 64];
#pragma unroll
    for (int j2 = 0; j2 < 4; ++j2) {
      uint4 pk;
      pk.x = pk_bf16(bv[2 * j2].x, bv[2 * j2].y);
      pk.y = pk_bf16(bv[2 * j2].z, bv[2 * j2].w);
      pk.z = pk_bf16(bv[2 * j2 + 1].x, bv[2 * j2 + 1].y);
      pk.w = pk_bf16(bv[2 * j2 + 1].z, bv[2 * j2 + 1].w);
      *(uint4*)(wb + (((hf4 + j2) ^ rB7) << 3)) = pk;
    }
  }

#pragma unroll 1
  for (int t = 0; t < NKT; ++t) {
    int d = t & 1;
    asm volatile("s_waitcnt vmcnt(0) lgkmcnt(0)" ::: "memory");
    __builtin_amdgcn_s_barrier();
    __builtin_amdgcn_sched_barrier(0);

    // issue next-tile staging loads first (longest latency)
    float4 bv[8];
    if (t + 1 < NKT) {
#pragma unroll
      for (int j = 0; j < 8; ++j) bv[j] = bsrc[(t + 1) * 16 + j];
#pragma unroll
      for (int c = 0; c < 4; ++c)
        g2l16(aptr[c] + (t + 1) * 64, &lA[d ^ 1][(c * 512 + tid) * 8]);
    }

    const u16* Ab = &lA[d][0];
    const u16* Bb = &lB[d][0];
    // ds_reads in consumption order: af[0], all B, af[1..7]
    bf16x8 af[8], af2[8], bf[4], bf2v[4];
    af[0]  = *(const bf16x8*)(Ab + adA[0][0]);
    af2[0] = *(const bf16x8*)(Ab + adA[0][1]);
#pragma unroll
    for (int j = 0; j < 4; ++j) {
      bf[j]   = *(const bf16x8*)(Bb + adB[j][0]);
      bf2v[j] = *(const bf16x8*)(Bb + adB[j][1]);
    }
#pragma unroll
    for (int f = 1; f < 8; ++f) {
      af[f]  = *(const bf16x8*)(Ab + adA[f][0]);
      af2[f] = *(const bf16x8*)(Ab + adA[f][1]);
    }

    __builtin_amdgcn_s_setprio(1);
#pragma unroll
    for (int mi = 0; mi < 8; ++mi) {
#pragma unroll
      for (int ni = 0; ni < 4; ++ni)
        acc[mi][ni] = __builtin_amdgcn_mfma_f32_16x16x32_bf16(
            af[mi], bf[ni], acc[mi][ni], 0, 0, 0);
#pragma unroll
      for (int ni = 0; ni < 4; ++ni)
        acc[mi][ni] = __builtin_amdgcn_mfma_f32_16x16x32_bf16(
            af2[mi], bf2v[ni], acc[mi][ni], 0, 0, 0);
    }
    __builtin_amdgcn_s_setprio(0);
    __builtin_amdgcn_sched_barrier(0);

    // convert + write B(t+1) after MFMA (latency fully hidden)
    if (t + 1 < NKT) {
      u16* wb = &lB[d ^ 1][rB * 64];
#pragma unroll
      for (int j2 = 0; j2 < 4; ++j2) {
        uint4 pk;
        pk.x = pk_bf16(bv[2 * j2].x, bv[2 * j2].y);
        pk.y = pk_bf16(bv[2 * j2].z, bv[2 * j2].w);
        pk.z = pk_bf16(bv[2 * j2 + 1].x, bv[2 * j2 + 1].y);
        pk.w = pk_bf16(bv[2 * j2 + 1].z, bv[2 * j2 + 1].w);
        *(uint4*)(wb + (((hf4 + j2) ^ rB7) << 3)) = pk;
      }
    }
  }

  // epilogue: C/D layout col=lane&15, row=quad*4+reg
#pragma unroll
  for (int mi = 0; mi < 8; ++mi) {
    int rb = wr * 128 + mi * 16 + quad * 4;
#pragma unroll
    for (int r = 0; r < 4; ++r) {
      int grow = m0 + rb + r;
      if (grow < cnt) {
        size_t o = (size_t)(base + grow) * OUTN + nt * 256 + wc * 64 + l16;
#pragma unroll
        for (int ni = 0; ni < 4; ++ni) {
          float v = acc[mi][ni][r];
          if (GELU) v = fast_gelu(v);
          O[o + ni * 16] = f32_to_bf16(v);
        }
      }
    }
  }
}

// ---------------- Combine: out[t] = g0*(y0+y1)[slot0] + g1*(y0+y1)[slot1]
__global__ __launch_bounds__(256) void combine_kernel(
    const u16* __restrict__ y, const int* __restrict__ tope,
    const float2* __restrict__ gate2, const int2* __restrict__ pos2,
    const int* __restrict__ counts, float* __restrict__ out) {
  const u16* y1 = y + (size_t)2 * T_TOK * H_DIM;
  int t = blockIdx.x;
  int pk = tope[t];
  int e0 = pk & 0xff, e1 = (pk >> 8) & 0xff;
  float2 g = gate2[t];
  int2 p = pos2[t];
  int hb0 = prefix_base(counts, e0);
  int hb1 = prefix_base(counts, e1);
  size_t s0 = (size_t)(hb0 + p.x) * H_DIM + threadIdx.x * 4;
  size_t s1 = (size_t)(hb1 + p.y) * H_DIM + threadIdx.x * 4;
  ushort4 a0 = *(const ushort4*)(y + s0);
  ushort4 a1 = *(const ushort4*)(y1 + s0);
  ushort4 b0 = *(const ushort4*)(y + s1);
  ushort4 b1 = *(const ushort4*)(y1 + s1);
  float4 o;
  o.x = g.x * (bf2f(a0.x) + bf2f(a1.x)) + g.y * (bf2f(b0.x) + bf2f(b1.x));
  o.y = g.x * (bf2f(a0.y) + bf2f(a1.y)) + g.y * (bf2f(b0.y) + bf2f(b1.y));
  o.z = g.x * (bf2f(a0.z) + bf2f(a1.z)) + g.y * (bf2f(b0.z) + bf2f(b1.z));
  o.w = g.x * (bf2f(a0.w) + bf2f(a1.w)) + g.y * (bf2f(b0.w) + bf2f(b1.w));
  *(float4*)(out + (size_t)t * H_DIM + threadIdx.x * 4) = o;
}

extern "C" void kernel_launch(void* const* d_in, const int* in_sizes, int n_in,
                              void* d_out, int out_size, void* d_ws, size_t ws_size,
                              hipStream_t stream) {
  const float* x  = (const float*)d_in[0];
  const float* rw = (const float*)d_in[1];
  const float* w1 = (const float*)d_in[2];
  const float* w2 = (const float*)d_in[3];
  float* out = (float*)d_out;

  // ws layout (bytes), total ~151.5 MB (same footprint as before):
  //   xb 0..16.8M | h 16.8..83.9M | y0 83.9..117.4M | y1 117.4..150.99M
  char* ws = (char*)d_ws;
  u16* xb       = (u16*)(ws);                        // 16,777,216
  u16* h        = (u16*)(ws + 16777216);             // 67,108,864
  u16* y        = (u16*)(ws + 83886080);             // 2 x 33,554,432 (y0,y1)
  int* tok_list = (int*)(ws + 150994944);            // 262,144
  int* tope     = (int*)(ws + 151257088);            // 32,768
  float2* gate2 = (float2*)(ws + 151289856);         // 65,536
  int2* pos2    = (int2*)(ws + 151355392);           // 65,536
  int* counts   = (int*)(ws + 151420928);            // 32

  prep_kernel<<<T_TOK / 4, 256, 0, stream>>>(x, rw, xb, tope, gate2, counts);
  build_kernel<<<T_TOK / 256, 256, 0, stream>>>(tope, counts, tok_list, pos2);
  // g1: gathered [cnt_e,1024](bf16) @ w1[e](f32->bf16 in-kernel) -> gelu -> h
  moe_gemm<16, 8, 1024, 1, H2, true, true>
      <<<NE * 32 * 8, 512, 0, stream>>>(xb, w1, h, tok_list, counts);
  // g2: h [cnt_e,2048] @ w2[e] (K split in 2 -> y0,y1 partials)
  moe_gemm<16, 4, 2048, 2, H_DIM, false, false>
      <<<NE * 32 * 4 * 2, 512, 0, stream>>>(h, w2, y, tok_list, counts);
  combine_kernel<<<T_TOK, 256, 0, stream>>>(y, tope, gate2, pos2, counts, out);
}

// Round 5
// 418.791 us; speedup vs baseline: 2.6751x; 2.6751x over previous
//
#include <hip/hip_runtime.h>
#include <stdint.h>
#include <math.h>

// Problem constants (B=4,S=2048 -> T=8192; H=1024; 2H=2048; E=8; K=2)
#define T_TOK 8192
#define H_DIM 1024
#define H2    2048
#define NE    8

typedef unsigned short u16;
typedef __attribute__((ext_vector_type(8))) short bf16x8;   // 8 bf16 in 4 VGPRs
typedef __attribute__((ext_vector_type(4))) float f32x4;    // MFMA 16x16 C/D

__device__ __forceinline__ u16 f32_to_bf16(float f) {
  union { float f; unsigned u; } c; c.f = f;
  unsigned u = c.u + 0x7fffu + ((c.u >> 16) & 1u);  // RNE
  return (u16)(u >> 16);
}
__device__ __forceinline__ float bf2f(u16 v) {
  union { unsigned u; float f; } c; c.u = (unsigned)v << 16; return c.f;
}

// fast gelu (tanh form), |err| vs exact erf-gelu <= ~1e-3 (absmax 1.56e-2
// vs threshold 4.9e-2, stable across rounds)
__device__ __forceinline__ float fast_gelu(float v) {
  float u = v * v;
  float z2 = v * fmaf(u, 0.1029437f, 2.3022078f);
  float e = __builtin_amdgcn_exp2f(z2);
  float r = __builtin_amdgcn_rcpf(1.0f + e);
  return v - v * r;
}

// async global->LDS, 16B per lane. LDS dest is wave-uniform base + lane*16;
// global address is per-lane (exploited for the XOR bank swizzle).
__device__ __forceinline__ void g2l16(const void* g, void* l) {
  __builtin_amdgcn_global_load_lds(
      (const __attribute__((address_space(1))) unsigned*)g,
      (__attribute__((address_space(3))) unsigned*)l, 16, 0, 0);
}

// exclusive prefix of 8 counts, computed per-block
__device__ __forceinline__ int prefix_base(const int* counts, int e) {
  int b = 0;
#pragma unroll
  for (int j = 0; j < NE; j++) b += (j < e) ? counts[j] : 0;
  return b;
}

// ---------------- Prep: router (blocks 0..2047) + w1 cvt only (rest).
// w2 cvt moved into g1's grid (heterogeneous fusion: BW-bound cvt hides
// under the compute-bound GEMM instead of serializing here).
__global__ __launch_bounds__(256) void prep_kernel(
    const float* __restrict__ x, const float* __restrict__ rw,
    const float* __restrict__ w1,
    u16* __restrict__ xb, u16* __restrict__ w1b,
    int* __restrict__ tope, float2* __restrict__ gate2,
    int* __restrict__ counts) {
  int blk = blockIdx.x;
  if (blk < T_TOK / 4) {
    int wave = threadIdx.x >> 6;
    int lane = threadIdx.x & 63;
    int t = blk * 4 + wave;
    const float4* x4 = (const float4*)(x + (size_t)t * H_DIM);
    const float4* rw4 = (const float4*)rw;
    u16* xbrow = xb + (size_t)t * H_DIM;

    double acc[NE];
#pragma unroll
    for (int e = 0; e < NE; e++) acc[e] = 0.0;
#pragma unroll
    for (int i = 0; i < 4; i++) {
      int c = lane + 64 * i;
      float4 xv = x4[c];
      ushort4 bv = make_ushort4(f32_to_bf16(xv.x), f32_to_bf16(xv.y),
                                f32_to_bf16(xv.z), f32_to_bf16(xv.w));
      *(ushort4*)(xbrow + c * 4) = bv;
#pragma unroll
      for (int e = 0; e < NE; e++) {
        float4 wv = rw4[e * 256 + c];
        acc[e] += (double)xv.x * wv.x + (double)xv.y * wv.y +
                  (double)xv.z * wv.z + (double)xv.w * wv.w;
      }
    }
#pragma unroll
    for (int off = 32; off >= 1; off >>= 1)
#pragma unroll
      for (int e = 0; e < NE; e++) acc[e] += __shfl_xor(acc[e], off, 64);

    if (lane == 0) {
      int e0 = 0; double v0 = acc[0];
#pragma unroll
      for (int e = 1; e < NE; e++) if (acc[e] > v0) { v0 = acc[e]; e0 = e; }
      int e1 = -1; double v1 = -1e300;
#pragma unroll
      for (int e = 0; e < NE; e++) if (e != e0 && acc[e] > v1) { v1 = acc[e]; e1 = e; }
      double ex = exp(v1 - v0);
      tope[t] = e0 | (e1 << 8);
      gate2[t] = make_float2((float)(1.0 / (1.0 + ex)), (float)(ex / (1.0 + ex)));
    }
  } else {
    int cb = blk - T_TOK / 4;
    if (cb == 0 && threadIdx.x < NE) counts[threadIdx.x] = 0;
    const int n4 = NE * H2 * H_DIM / 4;      // 4,194,304 float4s (w1)
    const int stride = 3072 * 256;
    const float4* s4 = (const float4*)w1;
    for (int i = cb * 256 + threadIdx.x; i < n4; i += stride) {
      float4 v = s4[i];
      *(ushort4*)(w1b + (size_t)i * 4) = make_ushort4(
          f32_to_bf16(v.x), f32_to_bf16(v.y), f32_to_bf16(v.z), f32_to_bf16(v.w));
    }
  }
}

// ---------------- Build expert lists: counting sort over 8 bins.
__global__ __launch_bounds__(256) void build_kernel(
    const int* __restrict__ tope, int* __restrict__ counts,
    int* __restrict__ tok_list, int2* __restrict__ pos2) {
  __shared__ int cts[4][NE];
  __shared__ int gbase[NE];
  int tid = threadIdx.x, lane = tid & 63, w = tid >> 6;
  int t = blockIdx.x * 256 + tid;
  int pk = tope[t];
  int e0 = pk & 0xff, e1 = (pk >> 8) & 0xff;
  unsigned long long lt = ((unsigned long long)1 << lane) - 1;

  int r0 = 0, r1 = 0;
#pragma unroll
  for (int e = 0; e < NE; e++) {
    unsigned long long b0 = __ballot(e0 == e);
    unsigned long long b1 = __ballot(e1 == e);
    int n0 = __popcll(b0), n1 = __popcll(b1);
    if (e0 == e) r0 = __popcll(b0 & lt);
    if (e1 == e) r1 = n0 + __popcll(b1 & lt);
    if (lane == 0) cts[w][e] = n0 + n1;
  }
  __syncthreads();
  if (tid < NE) {
    int bt = cts[0][tid] + cts[1][tid] + cts[2][tid] + cts[3][tid];
    gbase[tid] = atomicAdd(&counts[tid], bt);
  }
  __syncthreads();
  int off0 = gbase[e0] + r0;
  int off1 = gbase[e1] + r1;
#pragma unroll
  for (int wp = 0; wp < 4; wp++) {
    if (wp < w) { off0 += cts[wp][e0]; off1 += cts[wp][e1]; }
  }
  tok_list[e0 * T_TOK + off0] = t;
  tok_list[e1 * T_TOK + off1] = t;
  pos2[t] = make_int2(off0, off1);
}

// ---------------- Grouped GEMM, R5: 4-wave 128x256 tile, BK=32, dbuf,
// LDS 48 KB -> 2 BLOCKS/CU (the R0-R3 plateau was 1 block/CU: 40%
// per-block efficiency x 3 dispatch rounds; two co-resident blocks give
// cross-block stall overlap (m114/m97) + 2x finer makespan granularity).
//
// Per K-tile t (buf d=t&1), R3's proven minimum-sync loop:
//   vmcnt(0); s_barrier   // retires stage(t) issued a full tile ago
//   stage(t+1)->buf d^1   // 6 g2l16 (WAR-safe: reads of d^1 retired
//                         //  before every wave passed this barrier)
//   12 ds_read_b128 of buf d; setprio(1); 32 MFMA; setprio(0)
//
// Paired-row LDS layout for 32-col tiles: two logical rows per 128-B LDS
// row; slot s = ((r&1)*4 + c) ^ ((r>>1)&7). Every ds_read_b128 (64 lanes,
// fixed c=quad) fills 8 LDS rows x 8 slots exactly -> conflict-free; the
// g2l16 source is pre-swizzled to the inverse (both-sides-or-neither).
// XCD pinning: e = blockIdx&7 (bijective, gemm grid %8==0).
// CVT=true appends 1024 blocks converting w2 f32->bf16 (hidden under g1).
template <int NKT, int NT, int KFULL, int OUTN, bool GATHER, bool GELU, bool CVT>
__global__ __launch_bounds__(256, 2) void moe_gemm(
    const u16* __restrict__ A, const u16* __restrict__ W,
    u16* __restrict__ O, const int* __restrict__ tok_list,
    const int* __restrict__ counts,
    const float* __restrict__ cvt_src, u16* __restrict__ cvt_dst) {
  if (CVT && blockIdx.x >= 8 * 64 * NT) {
    int cb = blockIdx.x - 8 * 64 * NT;
    const int n4 = NE * H2 * H_DIM / 4;      // w2: 4,194,304 float4s
    const float4* s4 = (const float4*)cvt_src;
    for (int i = cb * 256 + threadIdx.x; i < n4; i += 1024 * 256) {
      float4 v = s4[i];
      *(ushort4*)(cvt_dst + (size_t)i * 4) = make_ushort4(
          f32_to_bf16(v.x), f32_to_bf16(v.y), f32_to_bf16(v.z), f32_to_bf16(v.w));
    }
    return;
  }
  int e = blockIdx.x & 7;
  int rem = blockIdx.x >> 3;
  int mt = rem / NT, nt = rem % NT;
  int cnt = counts[e];
  int m0 = mt * 128;
  if (m0 >= cnt) return;
  int base = prefix_base(counts, e);

  __shared__ u16 lA[2][4096];   // [dbuf][64 lr][8 slots][8 bf16] = 8 KB
  __shared__ u16 lB[2][8192];   // 16 KB each buf

  int tid = threadIdx.x;
  int ln = tid & 63, w = tid >> 6;
  int wc = w;                               // 1M x 4N wave grid
  int quad = ln >> 4, l16 = ln & 15;

  // ---- staging sources: unit u -> (lr=u>>3, s=u&7); logical l = s^(lr&7),
  // row r = lr*2 + (l>>2), chunk c = l&3 (8 bf16). LDS dest linear u*16B.
  const u16* We = W + (size_t)e * OUTN * KFULL;
  const u16* aptr[2]; const u16* bptr[4];
#pragma unroll
  for (int c2 = 0; c2 < 2; ++c2) {
    int u = c2 * 256 + tid;
    int lr = u >> 3, l = (u & 7) ^ (lr & 7);
    int r = lr * 2 + (l >> 2), c = l & 3;
    int ar = m0 + r; if (ar > cnt - 1) ar = cnt - 1;
    const u16* ab;
    if (GATHER) ab = A + (size_t)tok_list[e * T_TOK + ar] * KFULL;
    else        ab = A + (size_t)(base + ar) * KFULL;
    aptr[c2] = ab + c * 8;
  }
#pragma unroll
  for (int c2 = 0; c2 < 4; ++c2) {
    int u = c2 * 256 + tid;
    int lr = u >> 3, l = (u & 7) ^ (lr & 7);
    int r = lr * 2 + (l >> 2), c = l & 3;
    bptr[c2] = We + (size_t)(nt * 256 + r) * KFULL + c * 8;
  }

  // ---- read addresses (u16 units; row r, chunk quad)
  int adA[8], adB[4];
#pragma unroll
  for (int f = 0; f < 8; ++f) {
    int r = f * 16 + l16;
    adA[f] = (r >> 1) * 64 + ((((r & 1) * 4 + quad) ^ ((r >> 1) & 7)) << 3);
  }
#pragma unroll
  for (int j = 0; j < 4; ++j) {
    int r = wc * 64 + j * 16 + l16;
    adB[j] = (r >> 1) * 64 + ((((r & 1) * 4 + quad) ^ ((r >> 1) & 7)) << 3);
  }

  f32x4 acc[8][4];
#pragma unroll
  for (int i = 0; i < 8; i++)
#pragma unroll
    for (int j = 0; j < 4; j++)
#pragma unroll
      for (int r = 0; r < 4; r++) acc[i][j][r] = 0.f;

  // prologue: tile 0 in flight
#pragma unroll
  for (int c2 = 0; c2 < 2; ++c2) g2l16(aptr[c2], &lA[0][(c2 * 256 + tid) * 8]);
#pragma unroll
  for (int c2 = 0; c2 < 4; ++c2) g2l16(bptr[c2], &lB[0][(c2 * 256 + tid) * 8]);

#pragma unroll 1
  for (int t = 0; t < NKT; ++t) {
    int d = t & 1;
    asm volatile("s_waitcnt vmcnt(0)" ::: "memory");
    __builtin_amdgcn_s_barrier();
    __builtin_amdgcn_sched_barrier(0);

    if (t + 1 < NKT) {
#pragma unroll
      for (int c2 = 0; c2 < 2; ++c2)
        g2l16(aptr[c2] + (t + 1) * 32, &lA[d ^ 1][(c2 * 256 + tid) * 8]);
#pragma unroll
      for (int c2 = 0; c2 < 4; ++c2)
        g2l16(bptr[c2] + (t + 1) * 32, &lB[d ^ 1][(c2 * 256 + tid) * 8]);
    }

    bf16x8 af[8], bf[4];
    af[0] = *(const bf16x8*)(&lA[d][0] + adA[0]);
#pragma unroll
    for (int j = 0; j < 4; ++j) bf[j] = *(const bf16x8*)(&lB[d][0] + adB[j]);
#pragma unroll
    for (int f = 1; f < 8; ++f) af[f] = *(const bf16x8*)(&lA[d][0] + adA[f]);
    __builtin_amdgcn_sched_barrier(0);

    __builtin_amdgcn_s_setprio(1);
#pragma unroll
    for (int mi = 0; mi < 8; ++mi)
#pragma unroll
      for (int ni = 0; ni < 4; ++ni)
        acc[mi][ni] = __builtin_amdgcn_mfma_f32_16x16x32_bf16(
            af[mi], bf[ni], acc[mi][ni], 0, 0, 0);
    __builtin_amdgcn_s_setprio(0);
  }

  // epilogue: C/D layout col=lane&15, row=quad*4+reg
#pragma unroll
  for (int mi = 0; mi < 8; ++mi) {
    int rb = mi * 16 + quad * 4;
#pragma unroll
    for (int r = 0; r < 4; ++r) {
      int grow = m0 + rb + r;
      if (grow < cnt) {
        size_t o = (size_t)(base + grow) * OUTN + nt * 256 + wc * 64 + l16;
#pragma unroll
        for (int ni = 0; ni < 4; ++ni) {
          float v = acc[mi][ni][r];
          if (GELU) v = fast_gelu(v);
          O[o + ni * 16] = f32_to_bf16(v);
        }
      }
    }
  }
}

// ---------------- Combine: out[t] = g0*y[slot0(t)] + g1*y[slot1(t)]
__global__ __launch_bounds__(256) void combine_kernel(
    const u16* __restrict__ y, const int* __restrict__ tope,
    const float2* __restrict__ gate2, const int2* __restrict__ pos2,
    const int* __restrict__ counts, float* __restrict__ out) {
  int t = blockIdx.x;
  int pk = tope[t];
  int e0 = pk & 0xff, e1 = (pk >> 8) & 0xff;
  float2 g = gate2[t];
  int2 p = pos2[t];
  int hb0 = prefix_base(counts, e0);
  int hb1 = prefix_base(counts, e1);
  size_t s0 = (size_t)(hb0 + p.x) * H_DIM + threadIdx.x * 4;
  size_t s1 = (size_t)(hb1 + p.y) * H_DIM + threadIdx.x * 4;
  ushort4 a = *(const ushort4*)(y + s0);
  ushort4 b = *(const ushort4*)(y + s1);
  float4 o;
  o.x = g.x * bf2f(a.x) + g.y * bf2f(b.x);
  o.y = g.x * bf2f(a.y) + g.y * bf2f(b.y);
  o.z = g.x * bf2f(a.z) + g.y * bf2f(b.z);
  o.w = g.x * bf2f(a.w) + g.y * bf2f(b.w);
  *(float4*)(out + (size_t)t * H_DIM + threadIdx.x * 4) = o;
}

extern "C" void kernel_launch(void* const* d_in, const int* in_sizes, int n_in,
                              void* d_out, int out_size, void* d_ws, size_t ws_size,
                              hipStream_t stream) {
  const float* x  = (const float*)d_in[0];
  const float* rw = (const float*)d_in[1];
  const float* w1 = (const float*)d_in[2];
  const float* w2 = (const float*)d_in[3];
  float* out = (float*)d_out;

  // ws layout (bytes), total ~151.5 MB. y aliases w1b (dead after g1).
  char* ws = (char*)d_ws;
  u16* xb       = (u16*)(ws);                        // 16,777,216
  u16* w1b      = (u16*)(ws + 16777216);             // 33,554,432
  u16* y        = (u16*)(ws + 16777216);             // alias of w1b
  u16* w2b      = (u16*)(ws + 50331648);             // 33,554,432
  u16* h        = (u16*)(ws + 83886080);             // 67,108,864
  int* tok_list = (int*)(ws + 150994944);            // 262,144
  int* tope     = (int*)(ws + 151257088);            // 32,768
  float2* gate2 = (float2*)(ws + 151289856);         // 65,536
  int2* pos2    = (int2*)(ws + 151355392);           // 65,536
  int* counts   = (int*)(ws + 151420928);            // 32

  // prep: router (2048) + w1 cvt (3072)
  prep_kernel<<<T_TOK / 4 + 3072, 256, 0, stream>>>(x, rw, w1, xb, w1b,
                                                    tope, gate2, counts);
  build_kernel<<<T_TOK / 256, 256, 0, stream>>>(tope, counts, tok_list, pos2);
  // g1: gathered [cnt_e,1024](bf16) @ w1[e]^T -> gelu -> h [.,2048]
  //     + 1024 appended blocks convert w2 f32->bf16 (hidden under g1)
  moe_gemm<32, 8, 1024, H2, true, true, true>
      <<<8 * 64 * 8 + 1024, 256, 0, stream>>>(xb, w1b, h, tok_list, counts,
                                              w2, w2b);
  // g2: h [cnt_e,2048] @ w2[e]^T -> y [.,1024]
  moe_gemm<64, 4, 2048, H_DIM, false, false, false>
      <<<8 * 64 * 4, 256, 0, stream>>>(h, w2b, y, tok_list, counts,
                                       nullptr, nullptr);
  combine_kernel<<<T_TOK, 256, 0, stream>>>(y, tope, gate2, pos2, counts, out);
}